// Round 5
// baseline (1103.196 us; speedup 1.0000x reference)
//
#include <hip/hip_runtime.h>

#define T 3
#define E 500000
#define F 128
#define H 64
#define B 1024

#define BLK_E 64
#define LE 65  // xs row stride in floats; odd -> conflict-free transpose

// ---- helpers ----------------------------------------------------------

__device__ __forceinline__ float tanh_fast(float x) {
  // tanh(x) = 1 - 2/(exp(2x)+1); robust at +-inf
  float e = __expf(2.0f * x);
  return 1.0f - 2.0f / (e + 1.0f);
}

// ---- kernel 0: init ----------------------------------------------------

__global__ void k_init(unsigned* __restrict__ cnt, float* __restrict__ ssum) {
  int idx = blockIdx.x * blockDim.x + threadIdx.x;
  if (idx < T * B) {
    cnt[idx] = 0u;
    ssum[idx] = 0.0f;
  }
}

// ---- kernel 1: LDS-tiled MLP score ------------------------------------
// Block = 64 edges. Stage W1 (32KB) + transposed ea tile (xs[f][e], 33.3KB)
// in LDS via fully coalesced loads; each thread computes a 4-edge x 4-j
// register tile (acc = 16 VGPRs, spill-proof). Per f: 4 conflict-free
// ds_read_b32 + 1 broadcast ds_read_b128 feed 16 FMAs -> LDS pipe ~= VALU
// pipe. No max-subtraction: |score| <= ||W2||_1 ~ 6, exp() cannot overflow.

__global__ __launch_bounds__(256, 2) void k_score(
    const float* __restrict__ ea, const int* __restrict__ batch,
    const float* __restrict__ W1, const float* __restrict__ b1,
    const float* __restrict__ W2, const float* __restrict__ b2,
    float* __restrict__ exarr, float* __restrict__ ssum,
    unsigned* __restrict__ cnt) {
  __shared__ float ws[F * H];    // 32 KB, [f][j] stride 64
  __shared__ float xs[F * LE];   // 33.3 KB, [f][e] stride 65

  int t = blockIdx.y;
  int tid = threadIdx.x;
  int e0 = blockIdx.x * BLK_E;

  // stage W1[t]: 8192 floats, coalesced b32 (L2-hot after first block)
  const float* w1g = W1 + (size_t)t * F * H;
#pragma unroll
  for (int k = 0; k < (F * H) / 256; ++k)
    ws[tid + k * 256] = w1g[tid + k * 256];

  // stage ea tile, transposed into xs[f][e]; coalesced reads,
  // conflict-free writes (bank = (f + r) % 32)
  const float* eag = ea + ((size_t)t * E + e0) * (size_t)F;
  int emax = E - e0;  // edges available in this tile (>=1 by grid sizing)
#pragma unroll
  for (int k = 0; k < (BLK_E * F) / 256; ++k) {
    int idx = tid + k * 256;
    int r = idx >> 7;        // edge within tile
    int f = idx & 127;
    int rr = r < emax ? r : emax - 1;  // clamp tail rows
    xs[f * LE + r] = eag[(size_t)rr * F + f];
  }
  __syncthreads();

  // register-tiled GEMM: 4 edges (te) x 4 hidden (tj) per thread
  int te = tid & 15;   // edge group: edges 4*te .. 4*te+3
  int tj = tid >> 4;   // j group: j = 4*tj .. 4*tj+3

  float acc[4][4];
#pragma unroll
  for (int i = 0; i < 4; ++i)
#pragma unroll
    for (int j = 0; j < 4; ++j) acc[i][j] = 0.0f;

  const float4* wsq = (const float4*)ws;  // [f][16] float4
#pragma unroll 4
  for (int f = 0; f < F; ++f) {
    float x0 = xs[f * LE + 4 * te + 0];
    float x1 = xs[f * LE + 4 * te + 1];
    float x2 = xs[f * LE + 4 * te + 2];
    float x3 = xs[f * LE + 4 * te + 3];
    float4 w = wsq[f * 16 + tj];
    acc[0][0] = fmaf(x0, w.x, acc[0][0]);
    acc[0][1] = fmaf(x0, w.y, acc[0][1]);
    acc[0][2] = fmaf(x0, w.z, acc[0][2]);
    acc[0][3] = fmaf(x0, w.w, acc[0][3]);
    acc[1][0] = fmaf(x1, w.x, acc[1][0]);
    acc[1][1] = fmaf(x1, w.y, acc[1][1]);
    acc[1][2] = fmaf(x1, w.z, acc[1][2]);
    acc[1][3] = fmaf(x1, w.w, acc[1][3]);
    acc[2][0] = fmaf(x2, w.x, acc[2][0]);
    acc[2][1] = fmaf(x2, w.y, acc[2][1]);
    acc[2][2] = fmaf(x2, w.z, acc[2][2]);
    acc[2][3] = fmaf(x2, w.w, acc[2][3]);
    acc[3][0] = fmaf(x3, w.x, acc[3][0]);
    acc[3][1] = fmaf(x3, w.y, acc[3][1]);
    acc[3][2] = fmaf(x3, w.z, acc[3][2]);
    acc[3][3] = fmaf(x3, w.w, acc[3][3]);
  }

  // epilogue: tanh + dot with W2 slice -> 4 per-edge partials
  float b10 = b1[t * H + 4 * tj + 0], b11 = b1[t * H + 4 * tj + 1];
  float b12 = b1[t * H + 4 * tj + 2], b13 = b1[t * H + 4 * tj + 3];
  float w20 = W2[t * H + 4 * tj + 0], w21 = W2[t * H + 4 * tj + 1];
  float w22 = W2[t * H + 4 * tj + 2], w23 = W2[t * H + 4 * tj + 3];

  float psc[4];
#pragma unroll
  for (int i = 0; i < 4; ++i) {
    float s = tanh_fast(acc[i][0] + b10) * w20;
    s = fmaf(tanh_fast(acc[i][1] + b11), w21, s);
    s = fmaf(tanh_fast(acc[i][2] + b12), w22, s);
    s = fmaf(tanh_fast(acc[i][3] + b13), w23, s);
    psc[i] = s;
  }

  __syncthreads();          // done with xs as input tile
  float* red = xs;          // reuse: [64 edges][16 tj]
#pragma unroll
  for (int i = 0; i < 4; ++i) red[(4 * te + i) * 16 + tj] = psc[i];
  __syncthreads();

  if (tid < BLK_E) {
    int e = e0 + tid;
    if (e < E) {
      float sc = b2[t];
#pragma unroll
      for (int k = 0; k < 16; ++k) sc += red[tid * 16 + k];
      float ex = __expf(sc);
      int b = batch[(size_t)t * E + e];
      exarr[(size_t)t * E + e] = ex;
      atomicAdd(&ssum[t * B + b], ex);
      atomicAdd(&cnt[t * B + b], 1u);
    }
  }
}

// ---- kernel 2: prefix sums (edge-list offsets) ------------------------

__global__ void k_scan(const unsigned* __restrict__ cnt,
                       unsigned* __restrict__ offs,
                       unsigned* __restrict__ cursor) {
  __shared__ unsigned s[B];
  int tid = threadIdx.x;
  for (int t = 0; t < T; ++t) {
    unsigned v = cnt[t * B + tid];
    s[tid] = v;
    __syncthreads();
    for (int d = 1; d < B; d <<= 1) {
      unsigned x = (tid >= d) ? s[tid - d] : 0u;
      __syncthreads();
      s[tid] += x;
      __syncthreads();
    }
    unsigned excl = s[tid] - v;   // exclusive scan
    offs[t * B + tid] = excl;
    cursor[t * B + tid] = excl;
    __syncthreads();
  }
}

// ---- kernel 3: counting-sort scatter of edge ids ----------------------

__global__ __launch_bounds__(256) void k_scatter(
    const int* __restrict__ batch, unsigned* __restrict__ cursor,
    unsigned* __restrict__ eid) {
  int t = blockIdx.y;
  int e = blockIdx.x * 256 + threadIdx.x;
  if (e >= E) return;
  int b = batch[t * E + e];
  unsigned pos = atomicAdd(&cursor[t * B + b], 1u);
  eid[(size_t)t * E + pos] = e;
}

// ---- kernel 4: per-graph weighted gather-sum (float4) -----------------

__global__ __launch_bounds__(512) void k_pool(
    const float* __restrict__ ea, const float* __restrict__ exarr,
    const float* __restrict__ ssum, const unsigned* __restrict__ offs,
    const unsigned* __restrict__ cnt, const unsigned* __restrict__ eid,
    float* __restrict__ out) {
  int b = blockIdx.x;
  int f4 = threadIdx.x & 31;   // float4 index within row (32 x 16B = 512B)
  int g = threadIdx.x >> 5;    // 16 edge groups

  float4 total = {0.f, 0.f, 0.f, 0.f};
  for (int t = 0; t < T; ++t) {
    unsigned c = cnt[t * B + b];
    if (c == 0u) continue;
    unsigned o = offs[t * B + b];
    const unsigned* ids = eid + (size_t)t * E + o;
    const float* exs = exarr + (size_t)t * E;
    const float4* eat = (const float4*)(ea + (size_t)t * E * (size_t)F);
    float4 part = {0.f, 0.f, 0.f, 0.f};
#pragma unroll 4
    for (unsigned i = g; i < c; i += 16) {
      unsigned id = ids[i];                 // shared across 32-lane group
      float w = exs[id];
      float4 v = eat[(size_t)id * 32 + f4]; // 32 lanes x 16B = full row
      part.x = fmaf(w, v.x, part.x);
      part.y = fmaf(w, v.y, part.y);
      part.z = fmaf(w, v.z, part.z);
      part.w = fmaf(w, v.w, part.w);
    }
    float scale = (1.0f / 3.0f) / ssum[t * B + b];
    total.x = fmaf(part.x, scale, total.x);
    total.y = fmaf(part.y, scale, total.y);
    total.z = fmaf(part.z, scale, total.z);
    total.w = fmaf(part.w, scale, total.w);
  }

  __shared__ float4 red[512];
  red[threadIdx.x] = total;
  __syncthreads();
  if (threadIdx.x < 32) {
    float4 acc = red[threadIdx.x];
#pragma unroll
    for (int gg = 1; gg < 16; ++gg) {
      float4 v = red[gg * 32 + threadIdx.x];
      acc.x += v.x; acc.y += v.y; acc.z += v.z; acc.w += v.w;
    }
    ((float4*)out)[(size_t)b * 32 + threadIdx.x] = acc;
  }
}

// ---- launch ------------------------------------------------------------

extern "C" void kernel_launch(void* const* d_in, const int* in_sizes, int n_in,
                              void* d_out, int out_size, void* d_ws, size_t ws_size,
                              hipStream_t stream) {
  const float* ea    = (const float*)d_in[0];
  const int*   batch = (const int*)d_in[1];
  const float* W1    = (const float*)d_in[2];
  const float* b1    = (const float*)d_in[3];
  const float* W2    = (const float*)d_in[4];
  const float* b2    = (const float*)d_in[5];
  float* out = (float*)d_out;

  // workspace layout (~12.1 MB)
  float*    exarr  = (float*)d_ws;                          // T*E f32
  unsigned* eid    = (unsigned*)(exarr + (size_t)T * E);    // T*E u32
  unsigned* cnt    = (unsigned*)(eid + (size_t)T * E);      // T*B u32
  unsigned* offs   = cnt + T * B;                           // T*B u32
  unsigned* cursor = offs + T * B;                          // T*B u32
  float*    ssum   = (float*)(cursor + T * B);              // T*B f32

  k_init<<<(T * B + 255) / 256, 256, 0, stream>>>(cnt, ssum);

  dim3 gs((E + BLK_E - 1) / BLK_E, T);
  k_score<<<gs, 256, 0, stream>>>(ea, batch, W1, b1, W2, b2, exarr, ssum, cnt);
  k_scan<<<1, B, 0, stream>>>(cnt, offs, cursor);
  dim3 ge((E + 255) / 256, T);
  k_scatter<<<ge, 256, 0, stream>>>(batch, cursor, eid);
  k_pool<<<B, 512, 0, stream>>>(ea, exarr, ssum, offs, cnt, eid, out);
}

// Round 6
// 1005.169 us; speedup vs baseline: 1.0975x; 1.0975x over previous
//
#include <hip/hip_runtime.h>

#define T 3
#define E 500000
#define F 128
#define H 64
#define B 1024

#define BLK_E 64
#define LE 65   // xs row stride (odd -> <=2-way banks both phases)
#define LR 17   // red row stride (odd)

// ---- helpers ----------------------------------------------------------

__device__ __forceinline__ float tanh_fast(float x) {
  // tanh(x) = 1 - 2/(exp(2x)+1); robust at +-inf
  float e = __expf(2.0f * x);
  return 1.0f - 2.0f / (e + 1.0f);
}

// ---- kernel 0: zero accumulators --------------------------------------

__global__ void k_init(float* __restrict__ acc, float* __restrict__ ssum) {
  int idx = blockIdx.x * blockDim.x + threadIdx.x;
  if (idx < T * B * F) acc[idx] = 0.0f;
  if (idx < T * B) ssum[idx] = 0.0f;
}

// ---- kernel 1: fused score + exp + weighted scatter -------------------
// One pass over ea. Identity: out = (sum_i ex_i*ea_i) / (sum_i ex_i), so no
// second read of ea is needed. No max-subtraction: |score| <= ||W2||_1 ~ 6,
// exp() cannot overflow.
// Block = 64 edges. Stage transposed tile xs[f][e] (33KB). GEMM: 4-edge x
// 4-j register tiles; weights read from GLOBAL as float4 (W1[t] = 32KB,
// L1-resident) -> no W-LDS, 4 blocks/CU, LDS pipe balanced. Epilogue
// reduction stride-17 (conflict-free). Scatter: lanes span f, read xs
// columns (2-way free), 64-lane contiguous atomics into L2-resident acc.

__global__ __launch_bounds__(256, 4) void k_fused(
    const float* __restrict__ ea, const int* __restrict__ batch,
    const float* __restrict__ W1, const float* __restrict__ b1,
    const float* __restrict__ W2, const float* __restrict__ b2,
    float* __restrict__ acc, float* __restrict__ ssum) {
  __shared__ float xs[F * LE];       // 33.3 KB  [f][e]
  __shared__ float red[BLK_E * LR];  // 4.4 KB
  __shared__ float exl[BLK_E];
  __shared__ int   bbl[BLK_E];

  int t = blockIdx.y;
  int tid = threadIdx.x;
  int e0 = blockIdx.x * BLK_E;
  int emax = E - e0;  // >= 1 by grid sizing

  // stage ea tile transposed; global coalesced, LDS banks (f+e)%32 -> 2-way
  const float* eag = ea + ((size_t)t * E + e0) * (size_t)F;
#pragma unroll
  for (int k = 0; k < (BLK_E * F) / 256; ++k) {
    int idx = tid + k * 256;
    int r = idx >> 7;
    int f = idx & 127;
    int rr = r < emax ? r : emax - 1;  // clamp tail rows
    xs[f * LE + r] = eag[(size_t)rr * F + f];
  }
  __syncthreads();

  // register-tiled GEMM: 4 edges (te) x 4 hidden (tj) per thread
  int te = tid & 15;          // edges 4*te .. 4*te+3
  int tj = tid >> 4;          // j = 4*tj .. 4*tj+3  (0..15)

  float acc4[4][4];
#pragma unroll
  for (int i = 0; i < 4; ++i)
#pragma unroll
    for (int j = 0; j < 4; ++j) acc4[i][j] = 0.0f;

  const float4* wq = (const float4*)(W1 + (size_t)t * F * H);  // [f][16]
#pragma unroll 4
  for (int f = 0; f < F; ++f) {
    float x0 = xs[f * LE + 4 * te + 0];
    float x1 = xs[f * LE + 4 * te + 1];
    float x2 = xs[f * LE + 4 * te + 2];
    float x3 = xs[f * LE + 4 * te + 3];
    float4 w = wq[f * 16 + tj];        // global, L1-hot, 4 addrs/wave
    acc4[0][0] = fmaf(x0, w.x, acc4[0][0]);
    acc4[0][1] = fmaf(x0, w.y, acc4[0][1]);
    acc4[0][2] = fmaf(x0, w.z, acc4[0][2]);
    acc4[0][3] = fmaf(x0, w.w, acc4[0][3]);
    acc4[1][0] = fmaf(x1, w.x, acc4[1][0]);
    acc4[1][1] = fmaf(x1, w.y, acc4[1][1]);
    acc4[1][2] = fmaf(x1, w.z, acc4[1][2]);
    acc4[1][3] = fmaf(x1, w.w, acc4[1][3]);
    acc4[2][0] = fmaf(x2, w.x, acc4[2][0]);
    acc4[2][1] = fmaf(x2, w.y, acc4[2][1]);
    acc4[2][2] = fmaf(x2, w.z, acc4[2][2]);
    acc4[2][3] = fmaf(x2, w.w, acc4[2][3]);
    acc4[3][0] = fmaf(x3, w.x, acc4[3][0]);
    acc4[3][1] = fmaf(x3, w.y, acc4[3][1]);
    acc4[3][2] = fmaf(x3, w.z, acc4[3][2]);
    acc4[3][3] = fmaf(x3, w.w, acc4[3][3]);
  }

  // tanh + W2 slice -> per-edge partials; red stride 17 -> <=2-way banks
  float b10 = b1[t * H + 4 * tj + 0], b11 = b1[t * H + 4 * tj + 1];
  float b12 = b1[t * H + 4 * tj + 2], b13 = b1[t * H + 4 * tj + 3];
  float w20 = W2[t * H + 4 * tj + 0], w21 = W2[t * H + 4 * tj + 1];
  float w22 = W2[t * H + 4 * tj + 2], w23 = W2[t * H + 4 * tj + 3];

#pragma unroll
  for (int i = 0; i < 4; ++i) {
    float s = tanh_fast(acc4[i][0] + b10) * w20;
    s = fmaf(tanh_fast(acc4[i][1] + b11), w21, s);
    s = fmaf(tanh_fast(acc4[i][2] + b12), w22, s);
    s = fmaf(tanh_fast(acc4[i][3] + b13), w23, s);
    red[(4 * te + i) * LR + tj] = s;
  }
  __syncthreads();

  if (tid < BLK_E) {
    int e = e0 + tid;
    if (e < E) {
      float sc = b2[t];
#pragma unroll
      for (int k = 0; k < 16; ++k) sc += red[tid * LR + k];
      float ex = __expf(sc);
      int b = batch[(size_t)t * E + e];
      exl[tid] = ex;
      bbl[tid] = b;
      atomicAdd(&ssum[t * B + b], ex);
    }
  }
  __syncthreads();

  // scatter: wave wv handles 16 edges; lane l covers f=l and f=l+64.
  // xs column reads: bank (l+e)%32 -> 2-way free. Atomics: 64-lane
  // contiguous 256B regions into 1.5MB L2-resident acc.
  int wv = tid >> 6;
  int l = tid & 63;
  float* acct = acc + (size_t)t * B * F;
#pragma unroll 4
  for (int i = 0; i < 16; ++i) {
    int eloc = wv * 16 + i;
    if (e0 + eloc >= E) break;     // uniform (tail block only)
    float exv = exl[eloc];         // LDS broadcast
    int b = bbl[eloc];
    float v0 = xs[l * LE + eloc] * exv;
    float v1 = xs[(l + 64) * LE + eloc] * exv;
    atomicAdd(acct + (size_t)b * F + l, v0);
    atomicAdd(acct + (size_t)b * F + l + 64, v1);
  }
}

// ---- kernel 2: normalize + mean over types ----------------------------

__global__ __launch_bounds__(256) void k_final(
    const float* __restrict__ acc, const float* __restrict__ ssum,
    float* __restrict__ out) {
  int idx = blockIdx.x * 256 + threadIdx.x;  // b*F + f
  if (idx >= B * F) return;
  int b = idx >> 7;
  float s = 0.0f;
#pragma unroll
  for (int t = 0; t < T; ++t)
    s += acc[(size_t)t * B * F + idx] / ssum[t * B + b];
  out[idx] = s * (1.0f / 3.0f);
}

// ---- launch ------------------------------------------------------------

extern "C" void kernel_launch(void* const* d_in, const int* in_sizes, int n_in,
                              void* d_out, int out_size, void* d_ws, size_t ws_size,
                              hipStream_t stream) {
  const float* ea    = (const float*)d_in[0];
  const int*   batch = (const int*)d_in[1];
  const float* W1    = (const float*)d_in[2];
  const float* b1    = (const float*)d_in[3];
  const float* W2    = (const float*)d_in[4];
  const float* b2    = (const float*)d_in[5];
  float* out = (float*)d_out;

  // workspace: acc T*B*F f32 (1.5 MB) + ssum T*B f32
  float* acc  = (float*)d_ws;
  float* ssum = acc + (size_t)T * B * F;

  k_init<<<(T * B * F + 255) / 256, 256, 0, stream>>>(acc, ssum);

  dim3 gs((E + BLK_E - 1) / BLK_E, T);
  k_fused<<<gs, 256, 0, stream>>>(ea, batch, W1, b1, W2, b2, acc, ssum);

  k_final<<<(B * F + 255) / 256, 256, 0, stream>>>(acc, ssum, out);
}